// Round 5
// baseline (233.489 us; speedup 1.0000x reference)
//
#include <hip/hip_runtime.h>
#include <math.h>

// Group-limited MoE router, T=131072 tokens x E=256 experts.
// 8 lanes per token, one lane per expert-group (32 experts).
// Round 5: r3 structure (ds_swizzle, exact-sigmoid semantics) + fast-sigmoid
// first pass with margin checks; tokens whose selection gaps fall inside the
// error margin rerun with the exact sigmoid (bit-identical to r3).
// |sigma_tilde - sigma| <= ~4e-7  (arg err 6e-7 * ln2, exp2 1ulp, rcp 1ulp);
// margins: extraction gap 4e-6 (10x), group boundary 1.2e-5 (30x).

#define SWZF(x, mask) __int_as_float(__builtin_amdgcn_ds_swizzle(__float_as_int(x), (((mask) << 10) | 0x1F)))
#define SWZI(x, mask) __builtin_amdgcn_ds_swizzle((x), (((mask) << 10) | 0x1F))

__global__ __launch_bounds__(256) void router_topk_kernel(
    const float* __restrict__ logits,
    const float* __restrict__ bias,
    float* __restrict__ out_w,
    float* __restrict__ out_id,
    int T)
{
    const float NEGINF = -__builtin_inff();
    const float EM = 4e-6f;     // extraction-gap margin
    const float GM = 1.2e-5f;   // group-boundary margin
    const int tid = threadIdx.x;
    const int s = tid & 7;                      // expert-group owned by this lane
    const int token = blockIdx.x * 32 + (tid >> 3);
    if (token >= T) return;

    const float* row = logits + (size_t)token * 256 + s * 32;
    const float* brw = bias + s * 32;

    float v[8][4];
    int   ix[8][4];

    // ---- load 32 logits, sigmoid (fast or exact), add bias ----
    auto compute = [&](int exact) {
        #pragma unroll
        for (int c = 0; c < 8; ++c) {
            float4 l = ((const float4*)row)[c];
            float4 b = ((const float4*)brw)[c];
            #pragma unroll
            for (int k = 0; k < 4; ++k) {
                float x = (&l.x)[k];
                float sg;
                if (exact) {
                    sg = 1.0f / (1.0f + expf(-x));            // r3-identical
                } else {
                    float e = __builtin_amdgcn_exp2f(x * -1.4426950408889634f);
                    sg = __builtin_amdgcn_rcpf(1.0f + e);
                }
                v[c][k] = sg + (&b.x)[k];
            }
        }
    };

    float keepV = 0.0f; int keepI = 0;
    const int sbase8 = s << 3;

    auto select = [&](bool& flag) {
        // ---- (re)init indices ----
        #pragma unroll
        for (int c = 0; c < 8; ++c)
            #pragma unroll
            for (int k = 0; k < 4; ++k)
                ix[c][k] = s * 32 + c * 4 + k;

        // ---- group score: sum of top-2 of my 32 biased values ----
        float t1 = NEGINF, t2 = NEGINF;
        #pragma unroll
        for (int c = 0; c < 8; ++c) {
            #pragma unroll
            for (int k = 0; k < 4; ++k) {
                float val = v[c][k];
                t2 = fmaxf(t2, fminf(t1, val));
                t1 = fmaxf(t1, val);
            }
        }
        const float gs = t1 + t2;

        // ---- rank my group among the 8; keep top-4 (ties -> lower group) ----
        int rank = 0;
        #define RANKSTEP(m, hb) { \
            float gj = SWZF(gs, m); \
            rank += (gj > gs || (gj == gs && (s & (hb)))) ? 1 : 0; }
        RANKSTEP(1, 1) RANKSTEP(2, 2) RANKSTEP(3, 2)
        RANKSTEP(4, 4) RANKSTEP(5, 4) RANKSTEP(6, 4) RANKSTEP(7, 4)
        #undef RANKSTEP
        const bool selected = rank < 4;

        // ---- group-boundary gap check: 4th best vs 5th best group score ----
        float a  = selected ? NEGINF : gs;   // max -> 5th best
        float nb = selected ? -gs : NEGINF;  // max of -gs over selected -> -4th
        a  = fmaxf(a,  SWZF(a, 1));  nb = fmaxf(nb, SWZF(nb, 1));
        a  = fmaxf(a,  SWZF(a, 2));  nb = fmaxf(nb, SWZF(nb, 2));
        a  = fmaxf(a,  SWZF(a, 4));  nb = fmaxf(nb, SWZF(nb, 4));
        flag = ((-nb) - a) < GM;

        // ---- sort each chunk of 4 descending (ties -> lower idx first) ----
        #pragma unroll
        for (int c = 0; c < 8; ++c) {
            #define CE(x,y) { \
                bool sw = (v[c][x] < v[c][y]) || (v[c][x] == v[c][y] && ix[c][x] > ix[c][y]); \
                float tv = sw ? v[c][y] : v[c][x]; \
                float uv = sw ? v[c][x] : v[c][y]; \
                int   ti = sw ? ix[c][y] : ix[c][x]; \
                int   ui = sw ? ix[c][x] : ix[c][y]; \
                v[c][x] = tv; v[c][y] = uv; ix[c][x] = ti; ix[c][y] = ui; }
            CE(0,1) CE(2,3) CE(0,2) CE(1,3) CE(1,2)
            #undef CE
        }

        // ---- 9 rounds: extract global max; rounds 0-7 kept, round 8 only
        //      validates the 8th-vs-9th boundary gap ----
        float prev = 0.0f;
        #pragma unroll
        for (int r = 0; r < 9; ++r) {
            // depth-3 tournament over my 8 chunk heads; strict > keeps lower
            // chunk (= lower index) on ties.
            #define PICK(av, ai, bv_, bi_, rv, ri) { \
                bool t = ((bv_) > (av)); \
                rv = t ? (bv_) : (av); ri = t ? (bi_) : (ai); }
            float w0v, w1v, w2v, w3v, x0v, x1v, bv;
            int   w0i, w1i, w2i, w3i, x0i, x1i, bi;
            PICK(v[0][0], ix[0][0], v[1][0], ix[1][0], w0v, w0i)
            PICK(v[2][0], ix[2][0], v[3][0], ix[3][0], w1v, w1i)
            PICK(v[4][0], ix[4][0], v[5][0], ix[5][0], w2v, w2i)
            PICK(v[6][0], ix[6][0], v[7][0], ix[7][0], w3v, w3i)
            PICK(w0v, w0i, w1v, w1i, x0v, x0i)
            PICK(w2v, w2i, w3v, w3i, x1v, x1i)
            PICK(x0v, x0i, x1v, x1i, bv, bi)
            #undef PICK
            // mask unselected groups at the head (cheaper than masking 32 vals)
            bv = selected ? bv : NEGINF;
            // 8-lane butterfly argmax; index tie-break keeps lanes consistent
            #define BFLY(m) { \
                float ov = SWZF(bv, m); int oi = SWZI(bi, m); \
                bool t = (ov > bv) || (ov == bv && oi < bi); \
                bv = t ? ov : bv; bi = t ? oi : bi; }
            BFLY(1) BFLY(2) BFLY(4)
            #undef BFLY
            if (r > 0) flag = flag || ((prev - bv) < EM);
            prev = bv;
            if (r < 8) {
                if (s == r) { keepV = bv; keepI = bi; }
                const int d = (bi >> 2) - sbase8;  // my chunk if winner is mine
                #pragma unroll
                for (int c = 0; c < 8; ++c) {
                    bool hit = (d == c);
                    v[c][0]  = hit ? v[c][1]  : v[c][0];
                    ix[c][0] = hit ? ix[c][1] : ix[c][0];
                    v[c][1]  = hit ? v[c][2]  : v[c][1];
                    ix[c][1] = hit ? ix[c][2] : ix[c][1];
                    v[c][2]  = hit ? v[c][3]  : v[c][2];
                    ix[c][2] = hit ? ix[c][3] : ix[c][2];
                    v[c][3]  = hit ? NEGINF   : v[c][3];
                }
            }
        }
    };

    // ---- fast pass; rerun exactly if any margin was violated ----
    bool flag;
    compute(0);
    select(flag);
    if (flag) {
        compute(1);
        bool f2;
        select(f2);
    }

    // ---- recover sigmoid score, renormalize, scale, store (coalesced) ----
    float w = keepV - bias[keepI];
    float sum = w;
    sum += SWZF(sum, 1);
    sum += SWZF(sum, 2);
    sum += SWZF(sum, 4);
    w = w / (sum + 1e-20f) * 2.5f;

    out_w[(size_t)token * 8 + s]  = w;
    out_id[(size_t)token * 8 + s] = (float)keepI;
}

extern "C" void kernel_launch(void* const* d_in, const int* in_sizes, int n_in,
                              void* d_out, int out_size, void* d_ws, size_t ws_size,
                              hipStream_t stream) {
    const float* logits = (const float*)d_in[0];
    const float* bias   = (const float*)d_in[1];
    const int E = in_sizes[1];          // 256
    const int T = in_sizes[0] / E;      // 131072
    float* out_w  = (float*)d_out;
    float* out_id = out_w + (size_t)T * 8;
    const int blocks = (T + 31) / 32;
    router_topk_kernel<<<blocks, 256, 0, stream>>>(logits, bias, out_w, out_id, T);
}